// Round 7
// baseline (333.293 us; speedup 1.0000x reference)
//
#include <hip/hip_runtime.h>
#include <hip/hip_bf16.h>
#include <math.h>

// ---------------------------------------------------------------------------
// GAT 2-layer forward. CSR aggregation, bf16 gather table, ew recomputed
// inline (no ew2 array).
//
// Once per call: counting-sort edges by dst -> rowptr[N+1], esrc[]
//   scatter is dst-partitioned (8 ranges, XCD-affine via blockIdx%8).
// Per layer:
//   1) gemm_fused: h = x@W^T -> hq[n][c] packed bf16x2 + fused si/sj scores
//      (+ zeroes Z for the following z_sum)
//   2) z_sum (node-parallel): Z[hd] = sum_e exp(leaky(si[n]+sj[src]))
//      (global softmax denom; max-shift skipped — logits bounded,
//      mathematically identical)
//   3) csr_aggregate: one wave per dst node (scalarized CSR walk), weight
//      recomputed inline from si/sj; acc += w * hq[src]; epilogue
//      normalizes by Z, head-mean + bias (+relu), single write.
// ---------------------------------------------------------------------------

__device__ __forceinline__ unsigned f2bf(float x) {  // fp32 -> bf16 (RNE)
  unsigned u = __float_as_uint(x);
  return (u + 0x7fffu + ((u >> 16) & 1u)) >> 16;
}
__device__ __forceinline__ float bflo(unsigned p) { return __uint_as_float(p << 16); }
__device__ __forceinline__ float bfhi(unsigned p) { return __uint_as_float(p & 0xffff0000u); }

// Register-tiled GEMM + fused scores. Block: 256 = 32 thread-cols x 8 rows.
template <int FIN>
__global__ __launch_bounds__(256) void gemm_fused(
    const float* __restrict__ x, const float* __restrict__ W,
    const float* __restrict__ att, unsigned* __restrict__ hq,
    float* __restrict__ si, float* __restrict__ sj,
    float* __restrict__ Z, int N) {
  __shared__ __align__(16) float xs[32][68];
  __shared__ __align__(16) float ws[32][132];

  const int tid = threadIdx.x;
  const int tc = tid & 31;
  const int tr = tid >> 5;
  const int lane = tid & 63;
  const int n0 = blockIdx.x * 64;

  if (blockIdx.x == 0 && tid < 2) Z[tid] = 0.f;  // consumer is a later dispatch

  const float4* x4 = (const float4*)x;
  const float4* W4 = (const float4*)W;

  float acc[8][4];
#pragma unroll
  for (int i = 0; i < 8; ++i)
#pragma unroll
    for (int j = 0; j < 4; ++j) acc[i][j] = 0.f;

  for (int kc = 0; kc < FIN; kc += 32) {
    const int kc4 = kc >> 2;
    __syncthreads();
#pragma unroll
    for (int r = 0; r < 2; ++r) {
      int i = tid + r * 256;
      int node = i >> 3, kq = i & 7;
      int gn = n0 + node;
      float4 v = make_float4(0.f, 0.f, 0.f, 0.f);
      if (gn < N) v = x4[(size_t)gn * (FIN / 4) + kc4 + kq];
      xs[kq * 4 + 0][node] = v.x;
      xs[kq * 4 + 1][node] = v.y;
      xs[kq * 4 + 2][node] = v.z;
      xs[kq * 4 + 3][node] = v.w;
    }
#pragma unroll
    for (int r = 0; r < 4; ++r) {
      int i = tid + r * 256;
      int col = i >> 3, kq = i & 7;
      float4 v = W4[(size_t)col * (FIN / 4) + kc4 + kq];
      ws[kq * 4 + 0][col] = v.x;
      ws[kq * 4 + 1][col] = v.y;
      ws[kq * 4 + 2][col] = v.z;
      ws[kq * 4 + 3][col] = v.w;
    }
    __syncthreads();
#pragma unroll
    for (int k = 0; k < 32; ++k) {
      float4 wv = *(const float4*)&ws[k][tc * 4];
      float4 a0 = *(const float4*)&xs[k][tr * 8];
      float4 a1 = *(const float4*)&xs[k][tr * 8 + 4];
      float av[8] = {a0.x, a0.y, a0.z, a0.w, a1.x, a1.y, a1.z, a1.w};
      float wvv[4] = {wv.x, wv.y, wv.z, wv.w};
#pragma unroll
      for (int i = 0; i < 8; ++i)
#pragma unroll
        for (int j = 0; j < 4; ++j) acc[i][j] += av[i] * wvv[j];
    }
  }

  // ------- epilogue: pack bf16x2 h + fused attention scores -------
  const int hd = tc >> 4;
  const int ch = (tc & 15) * 4;
  float ai[4], aj[4];
#pragma unroll
  for (int j = 0; j < 4; ++j) {
    ai[j] = att[hd * 128 + ch + j];
    aj[j] = att[hd * 128 + 64 + ch + j];
  }
#pragma unroll
  for (int i = 0; i < 8; ++i) {
    int node = n0 + tr * 8 + i;
    float sip = 0.f, sjp = 0.f;
    unsigned w[4];
#pragma unroll
    for (int j = 0; j < 4; ++j) {
      float v = acc[i][j];
      sip += v * ai[j];
      sjp += v * aj[j];
      float other = __shfl_xor(v, 16, 64);  // partner head, same channel
      float h0 = (tc < 16) ? v : other;
      float h1 = (tc < 16) ? other : v;
      w[j] = f2bf(h0) | (f2bf(h1) << 16);
    }
#pragma unroll
    for (int off = 8; off; off >>= 1) {
      sip += __shfl_down(sip, off, 64);
      sjp += __shfl_down(sjp, off, 64);
    }
    bool valid = node < N;
    if (valid && tc < 16) {
      *(uint4*)&hq[(size_t)node * 64 + ch] = make_uint4(w[0], w[1], w[2], w[3]);
    }
    if (valid && (lane & 15) == 0) {
      int hh = (lane >> 4) & 1;
      si[node * 2 + hh] = sip;
      sj[node * 2 + hh] = sjp;
    }
  }
}

// node-parallel Z reduction: thread n walks its CSR range, no stores
__global__ __launch_bounds__(256) void z_sum(
    const int* __restrict__ rowptr, const int* __restrict__ esrc,
    const float2* __restrict__ si2, const float2* __restrict__ sj2,
    float* __restrict__ Z, int N) {
  float z0 = 0.f, z1 = 0.f;
  int tid = blockIdx.x * blockDim.x + threadIdx.x;
  int stride = gridDim.x * blockDim.x;
  for (int n = tid; n < N; n += stride) {
    int beg = rowptr[n], end = rowptr[n + 1];
    float2 siv = si2[n];
    for (int k = beg; k < end; ++k) {
      int s = esrc[k];
      float2 sjv = sj2[s];
      float a0 = siv.x + sjv.x;
      float a1 = siv.y + sjv.y;
      a0 = a0 >= 0.f ? a0 : 0.2f * a0;
      a1 = a1 >= 0.f ? a1 : 0.2f * a1;
      z0 += __expf(a0); z1 += __expf(a1);
    }
  }
  __shared__ float r0[4], r1[4];
  int lane = threadIdx.x & 63, w = threadIdx.x >> 6;
#pragma unroll
  for (int off = 32; off; off >>= 1) {
    z0 += __shfl_down(z0, off, 64);
    z1 += __shfl_down(z1, off, 64);
  }
  if (lane == 0) { r0[w] = z0; r1[w] = z1; }
  __syncthreads();
  if (threadIdx.x == 0) {
    atomicAdd(&Z[0], r0[0] + r0[1] + r0[2] + r0[3]);
    atomicAdd(&Z[1], r1[0] + r1[1] + r1[2] + r1[3]);
  }
}

// -------------------- counting sort by dst --------------------
__global__ __launch_bounds__(256) void hist_dst(
    const int* __restrict__ dstE, int* __restrict__ deg, int E, int Etot) {
  int tid = blockIdx.x * blockDim.x + threadIdx.x;
  int stride = gridDim.x * blockDim.x;
  for (int e = tid; e < Etot; e += stride) {
    int d = (e < E) ? dstE[e] : e - E;
    atomicAdd(&deg[d], 1);
  }
}

__global__ __launch_bounds__(256) void scan_blocks(
    const int* __restrict__ deg, int* __restrict__ rowptr,
    int* __restrict__ bsum, int N) {
  __shared__ int ts[256];
  int b = blockIdx.x, t = threadIdx.x;
  int base = b * 1024 + t * 4;
  int v[4];
#pragma unroll
  for (int j = 0; j < 4; ++j) v[j] = (base + j < N) ? deg[base + j] : 0;
  int tot = v[0] + v[1] + v[2] + v[3];
  ts[t] = tot;
  __syncthreads();
#pragma unroll
  for (int off = 1; off < 256; off <<= 1) {
    int x = (t >= off) ? ts[t - off] : 0;
    __syncthreads();
    ts[t] += x;
    __syncthreads();
  }
  int run = ts[t] - tot;
#pragma unroll
  for (int j = 0; j < 4; ++j) {
    if (base + j < N) rowptr[base + j] = run;
    run += v[j];
  }
  if (t == 255) bsum[b] = ts[255];
}

__global__ __launch_bounds__(64) void scan_bsum(int* __restrict__ bsum, int nb) {
  __shared__ int ls[256];
  int t = threadIdx.x;
  for (int i = t; i < nb; i += 64) ls[i] = bsum[i];
  __syncthreads();
  if (t == 0) {
    int run = 0;
    for (int i = 0; i < nb; ++i) { int v = ls[i]; ls[i] = run; run += v; }
  }
  __syncthreads();
  for (int i = t; i < nb; i += 64) bsum[i] = ls[i];
}

__global__ __launch_bounds__(256) void scan_finish(
    int* __restrict__ rowptr, const int* __restrict__ bsum,
    int* __restrict__ cursor, int N, int Etot) {
  int tid = blockIdx.x * blockDim.x + threadIdx.x;
  int stride = gridDim.x * blockDim.x;
  for (int i = tid; i < N; i += stride) {
    int v = rowptr[i] + bsum[i >> 10];
    rowptr[i] = v;
    cursor[i] = v;
  }
  if (tid == 0) rowptr[N] = Etot;
}

// dst-partitioned scatter (8 ranges, XCD-affine via blockIdx%8): cursor
// atomics + esrc stores stay resident in one L2 slice. Locality-only
// heuristic — correctness never depends on the mapping.
__global__ __launch_bounds__(256) void scatter_part(
    const int* __restrict__ srcE, const int* __restrict__ dstE,
    int* __restrict__ cursor, int* __restrict__ esrc,
    int E, int Etot, int step) {
  const int p = blockIdx.x & 7;
  const int sub = blockIdx.x >> 3;
  const int nsub = gridDim.x >> 3;
  const int lo = p * step;
  const int hi = lo + step;
  int stride = nsub * 256;
  for (int e = sub * 256 + threadIdx.x; e < Etot; e += stride) {
    int d = (e < E) ? dstE[e] : e - E;
    if (d >= lo && d < hi) {
      int s = (e < E) ? srcE[e] : d;
      int pos = atomicAdd(&cursor[d], 1);
      esrc[pos] = s;
    }
  }
}

// one wave per dst node (scalarized): weight recomputed inline,
// acc += w * hq[src], fused head-mean + bias (+relu) epilogue
__global__ __launch_bounds__(256) void csr_aggregate(
    const int* __restrict__ rowptr, const int* __restrict__ esrc,
    const unsigned* __restrict__ hq, const float2* __restrict__ si2,
    const float2* __restrict__ sj2, const float* __restrict__ Z,
    const float* __restrict__ bias, float* __restrict__ out,
    int N, int do_relu) {
  int lane = threadIdx.x & 63;
  int wid = (blockIdx.x * blockDim.x + threadIdx.x) >> 6;
  int nw = (gridDim.x * blockDim.x) >> 6;
  float z0 = 1.f / (Z[0] + 1e-10f);
  float z1 = 1.f / (Z[1] + 1e-10f);
  float bv = bias[lane];
  for (int n0 = wid; n0 < N; n0 += nw) {
    // n is wave-uniform; force SGPR so the rowptr/esrc/sj2 chain is scalar
    int n = __builtin_amdgcn_readfirstlane(n0);
    int beg = rowptr[n], end = rowptr[n + 1];
    float2 siv = si2[n];
    float acc0 = 0.f, acc1 = 0.f;
    int k = beg;
    for (; k + 4 <= end; k += 4) {
      int s0 = esrc[k], s1 = esrc[k + 1], s2 = esrc[k + 2], s3 = esrc[k + 3];
      float2 j0 = sj2[s0], j1 = sj2[s1], j2 = sj2[s2], j3 = sj2[s3];
      unsigned p0 = hq[(size_t)s0 * 64 + lane];
      unsigned p1 = hq[(size_t)s1 * 64 + lane];
      unsigned p2 = hq[(size_t)s2 * 64 + lane];
      unsigned p3 = hq[(size_t)s3 * 64 + lane];
      float a00 = siv.x + j0.x, a01 = siv.y + j0.y;
      float a10 = siv.x + j1.x, a11 = siv.y + j1.y;
      float a20 = siv.x + j2.x, a21 = siv.y + j2.y;
      float a30 = siv.x + j3.x, a31 = siv.y + j3.y;
      a00 = a00 >= 0.f ? a00 : 0.2f * a00;  a01 = a01 >= 0.f ? a01 : 0.2f * a01;
      a10 = a10 >= 0.f ? a10 : 0.2f * a10;  a11 = a11 >= 0.f ? a11 : 0.2f * a11;
      a20 = a20 >= 0.f ? a20 : 0.2f * a20;  a21 = a21 >= 0.f ? a21 : 0.2f * a21;
      a30 = a30 >= 0.f ? a30 : 0.2f * a30;  a31 = a31 >= 0.f ? a31 : 0.2f * a31;
      float w00 = __expf(a00), w01 = __expf(a01);
      float w10 = __expf(a10), w11 = __expf(a11);
      float w20 = __expf(a20), w21 = __expf(a21);
      float w30 = __expf(a30), w31 = __expf(a31);
      acc0 += bflo(p0) * w00 + bflo(p1) * w10 + bflo(p2) * w20 + bflo(p3) * w30;
      acc1 += bfhi(p0) * w01 + bfhi(p1) * w11 + bfhi(p2) * w21 + bfhi(p3) * w31;
    }
    for (; k < end; ++k) {
      int s = esrc[k];
      float2 jv = sj2[s];
      unsigned p = hq[(size_t)s * 64 + lane];
      float a0 = siv.x + jv.x, a1 = siv.y + jv.y;
      a0 = a0 >= 0.f ? a0 : 0.2f * a0;
      a1 = a1 >= 0.f ? a1 : 0.2f * a1;
      acc0 += bflo(p) * __expf(a0);
      acc1 += bfhi(p) * __expf(a1);
    }
    float r = 0.5f * (acc0 * z0 + acc1 * z1) + bv;
    if (do_relu) r = fmaxf(r, 0.f);
    out[(size_t)n * 64 + lane] = r;
  }
}

extern "C" void kernel_launch(void* const* d_in, const int* in_sizes, int n_in,
                              void* d_out, int out_size, void* d_ws, size_t ws_size,
                              hipStream_t stream) {
  const float* x    = (const float*)d_in[0];
  const int*   ei   = (const int*)d_in[1];   // [2, E] int32
  const float* W1   = (const float*)d_in[2];
  const float* att1 = (const float*)d_in[3];
  const float* b1   = (const float*)d_in[4];
  const float* W2   = (const float*)d_in[5];
  const float* att2 = (const float*)d_in[6];
  const float* b2   = (const float*)d_in[7];
  float* out = (float*)d_out;

  const int N = in_sizes[0] / 128;   // 50000
  const int E = in_sizes[1] / 2;     // 800000
  const int Etot = E + N;
  const int* srcE = ei;
  const int* dstE = ei + E;

  // workspace layout (all segments 16B-aligned)
  unsigned* hq = (unsigned*)d_ws;                 // N*64 packed bf16x2
  float* si    = (float*)(hq + (size_t)N * 64);   // N*2
  float* sj    = si + (size_t)N * 2;              // N*2
  float* Z     = sj + (size_t)N * 2;              // 4
  float* x2    = Z + 4;                           // N*64
  int* rowptr  = (int*)(x2 + (size_t)N * 64);     // N+1
  int* cursor  = rowptr + (N + 1);                // N (deg histogram too)
  int* esrc    = cursor + N;                      // Etot
  int* bsum    = esrc + Etot;                     // up to 64

  dim3 blk(256);
  int nb = (N + 1023) / 1024;
  int ntiles = (N + 63) / 64;
  int step = (N + 7) / 8;

  // ---------- CSR build (shared by both layers) ----------
  hipMemsetAsync(cursor, 0, (size_t)N * sizeof(int), stream);
  hist_dst<<<2048, blk, 0, stream>>>(dstE, cursor, E, Etot);
  scan_blocks<<<nb, blk, 0, stream>>>(cursor, rowptr, bsum, N);
  scan_bsum<<<1, 64, 0, stream>>>(bsum, nb);
  scan_finish<<<256, blk, 0, stream>>>(rowptr, bsum, cursor, N, Etot);
  scatter_part<<<2048, blk, 0, stream>>>(srcE, dstE, cursor, esrc, E, Etot, step);

  // ---------------- layer 1 ----------------
  gemm_fused<128><<<ntiles, blk, 0, stream>>>(x, W1, att1, hq, si, sj, Z, N);
  z_sum<<<256, blk, 0, stream>>>(rowptr, esrc, (const float2*)si,
                                 (const float2*)sj, Z, N);
  csr_aggregate<<<4096, blk, 0, stream>>>(rowptr, esrc, hq, (const float2*)si,
                                          (const float2*)sj, Z, b1, x2, N, 1);

  // ---------------- layer 2 ----------------
  gemm_fused<64><<<ntiles, blk, 0, stream>>>(x2, W2, att2, hq, si, sj, Z, N);
  z_sum<<<256, blk, 0, stream>>>(rowptr, esrc, (const float2*)si,
                                 (const float2*)sj, Z, N);
  csr_aggregate<<<4096, blk, 0, stream>>>(rowptr, esrc, hq, (const float2*)si,
                                          (const float2*)sj, Z, b2, out, N, 0);
}